// Round 1
// baseline (98.810 us; speedup 1.0000x reference)
//
#include <hip/hip_runtime.h>

// Problem constants (from reference)
constexpr int kB   = 4;
constexpr int kC   = 64;
constexpr int kH   = 32;
constexpr int kW   = 32;
constexpr int kO   = 128;
constexpr int kG   = 4;
constexpr int kCS  = 64;
constexpr int kSEG = kC * 9;        // 576
constexpr int kE   = kO * kG * kCS; // 32768
constexpr int kHW  = kH * kW;       // 1024

// Kernel 1: W[o][s] = sum_g means[o,g] * count(dest==o*G+g && col_idx==s)
__global__ __launch_bounds__(256) void build_w_kernel(
    const float* __restrict__ means,
    const int*   __restrict__ col_idx,
    const int*   __restrict__ dest,
    float*       __restrict__ Wbuf)
{
    int e = blockIdx.x * blockDim.x + threadIdx.x;
    if (e >= kE) return;
    int og = dest[e];
    int o  = og >> 2;   // / kG
    int g  = og & 3;    // % kG
    int s  = col_idx[e];
    atomicAdd(&Wbuf[o * kSEG + s], means[o * kG + g]);
}

// Kernel 2: 3x3 conv, pad=1, weights Wbuf[o][c*9 + kh*3 + kw], bias added.
// One block per (b,o). 256 threads, each computes 4 horizontally-contiguous
// output pixels. Per channel: stage 34x34 haloed tile in LDS (stride 36).
constexpr int kTS = 36; // LDS row stride (34 cols + pad)

__global__ __launch_bounds__(256) void conv_kernel(
    const float* __restrict__ x,
    const float* __restrict__ Wbuf,
    const float* __restrict__ bias,
    float*       __restrict__ out)
{
    __shared__ float tile[34 * kTS];

    const int b = blockIdx.x >> 7;    // / kO
    const int o = blockIdx.x & 127;   // % kO

    const int t   = threadIdx.x;
    const int px0 = t * 4;            // first output pixel (row-major in 32x32)
    const int r   = px0 >> 5;         // output row
    const int c0  = px0 & 31;         // output col of first pixel

    float acc0 = 0.f, acc1 = 0.f, acc2 = 0.f, acc3 = 0.f;

    const float* xb = x + (size_t)b * kC * kHW;

    for (int ch = 0; ch < kC; ++ch) {
        __syncthreads();   // protect prior-iteration tile reads
        // stage 34x34 haloed tile (zeros outside)
        for (int i = t; i < 34 * 34; i += 256) {
            int rr = i / 34;
            int cc = i - rr * 34;
            int hr = rr - 1;
            int hc = cc - 1;
            float v = 0.f;
            if (hr >= 0 && hr < kH && hc >= 0 && hc < kW)
                v = xb[ch * kHW + hr * kW + hc];
            tile[rr * kTS + cc] = v;
        }
        __syncthreads();

        // block-uniform weights for this channel
        float w[9];
        #pragma unroll
        for (int k = 0; k < 9; ++k)
            w[k] = Wbuf[o * kSEG + ch * 9 + k];

        #pragma unroll
        for (int kh = 0; kh < 3; ++kh) {
            float xv[6];
            #pragma unroll
            for (int j = 0; j < 6; ++j)
                xv[j] = tile[(r + kh) * kTS + c0 + j];
            #pragma unroll
            for (int kw = 0; kw < 3; ++kw) {
                const float wv = w[kh * 3 + kw];
                acc0 += wv * xv[kw + 0];
                acc1 += wv * xv[kw + 1];
                acc2 += wv * xv[kw + 2];
                acc3 += wv * xv[kw + 3];
            }
        }
    }

    const float bo = bias[o];
    float4 res = make_float4(acc0 + bo, acc1 + bo, acc2 + bo, acc3 + bo);
    *reinterpret_cast<float4*>(&out[((size_t)(b * kO + o)) * kHW + px0]) = res;
}

extern "C" void kernel_launch(void* const* d_in, const int* in_sizes, int n_in,
                              void* d_out, int out_size, void* d_ws, size_t ws_size,
                              hipStream_t stream)
{
    const float* x       = (const float*)d_in[0];
    const float* means   = (const float*)d_in[1];
    const float* bias    = (const float*)d_in[2];
    const int*   col_idx = (const int*)d_in[3];
    const int*   dest    = (const int*)d_in[4];
    float*       out     = (float*)d_out;
    float*       Wbuf    = (float*)d_ws;   // kO * kSEG floats = 288 KB

    hipMemsetAsync(Wbuf, 0, (size_t)kO * kSEG * sizeof(float), stream);
    build_w_kernel<<<kE / 256, 256, 0, stream>>>(means, col_idx, dest, Wbuf);
    conv_kernel<<<kB * kO, 256, 0, stream>>>(x, Wbuf, bias, out);
}

// Round 2
// 33.003 us; speedup vs baseline: 2.9940x; 2.9940x over previous
//
#include <hip/hip_runtime.h>

// Problem constants
constexpr int kB   = 4;
constexpr int kC   = 64;
constexpr int kH   = 32;
constexpr int kW   = 32;
constexpr int kO   = 128;
constexpr int kG   = 4;
constexpr int kCS  = 64;
constexpr int kSEG = kC * 9;   // 576
constexpr int kHW  = kH * kW;  // 1024
constexpr int kTILE = 34 * 34; // 1156 haloed elements

// Conv kernel, templated on number of channel chunks.
// Grid = NC * B * O blocks, 256 threads.
// blk -> o = blk&127, b = (blk>>7)&3, chunk = blk>>9.
// Each thread: col c = t&31, rows r0 = (t>>5)*4 .. +3 (vertical strip of 4 px).
// Weights for this (o, chunk) are built in LDS from col_idx/means (dest is
// repeat(arange(O*G), CS), so entries for o are e in [o*256, o*256+256)).
template <int NC, bool FINAL>
__global__ __launch_bounds__(256) void conv_kernel(
    const float* __restrict__ x,
    const float* __restrict__ means,
    const float* __restrict__ bias,
    const int*   __restrict__ col_idx,
    float*       __restrict__ outp)
{
    constexpr int CPC = kC / NC;   // channels per chunk
    constexpr int WCH = CPC * 9;   // weights per chunk

    __shared__ float tile[kTILE];
    __shared__ float wloc[WCH];

    const int blk   = blockIdx.x;
    const int o     = blk & (kO - 1);
    const int b     = (blk >> 7) & (kB - 1);
    const int chunk = blk >> 9;
    const int t     = threadIdx.x;

    // ---- build weight chunk in LDS ----
    for (int i = t; i < WCH; i += 256) wloc[i] = 0.f;
    __syncthreads();
    {
        // t indexes the 256 gather entries for this o: e = o*256 + t,
        // group g = t>>6 (since e = (o*G+g)*CS + j).
        const int s    = col_idx[o * (kG * kCS) + t];
        const int base = chunk * WCH;
        if (s >= base && s < base + WCH)
            atomicAdd(&wloc[s - base], means[o * kG + (t >> 6)]);
    }

    // ---- precompute staging indices (same every channel) ----
    int lidx[5], gofs[5];
    #pragma unroll
    for (int k = 0; k < 5; ++k) {
        const int i = t + k * 256;
        lidx[k] = (i < kTILE) ? i : -1;
        const int rr = i / 34;
        const int cc = i - rr * 34;
        const int hr = rr - 1, hc = cc - 1;
        gofs[k] = (i < kTILE && hr >= 0 && hr < kH && hc >= 0 && hc < kW)
                      ? hr * kW + hc : -1;
    }

    const int   c   = t & 31;
    const int   r0  = (t >> 5) * 4;
    const float* xb = x + ((size_t)b * kC + chunk * CPC) * kHW;

    float acc[4] = {0.f, 0.f, 0.f, 0.f};

    for (int ch = 0; ch < CPC; ++ch) {
        __syncthreads();   // also covers wloc build on first iteration
        #pragma unroll
        for (int k = 0; k < 5; ++k)
            if (lidx[k] >= 0)
                tile[lidx[k]] = (gofs[k] >= 0) ? xb[ch * kHW + gofs[k]] : 0.f;
        __syncthreads();

        float w[9];
        #pragma unroll
        for (int k = 0; k < 9; ++k) w[k] = wloc[ch * 9 + k];  // LDS broadcast

        // 6 rows x 3 cols of input for this thread's 4 output rows
        float xv[6][3];
        #pragma unroll
        for (int i = 0; i < 6; ++i)
            #pragma unroll
            for (int j = 0; j < 3; ++j)
                xv[i][j] = tile[(r0 + i) * 34 + c + j];

        #pragma unroll
        for (int i = 0; i < 4; ++i)
            #pragma unroll
            for (int kh = 0; kh < 3; ++kh)
                #pragma unroll
                for (int kw = 0; kw < 3; ++kw)
                    acc[i] += w[kh * 3 + kw] * xv[i + kh][kw];
    }

    float* dst = outp + (((size_t)chunk * kB + b) * kO + o) * kHW;
    if (FINAL) {
        const float bo = bias[o];
        #pragma unroll
        for (int i = 0; i < 4; ++i)
            dst[(r0 + i) * kW + c] = acc[i] + bo;
    } else {
        #pragma unroll
        for (int i = 0; i < 4; ++i)
            dst[(r0 + i) * kW + c] = acc[i];
    }
}

// Sum NC partials + bias -> out. float4 per thread.
template <int NC>
__global__ __launch_bounds__(256) void reduce_kernel(
    const float* __restrict__ part,
    const float* __restrict__ bias,
    float*       __restrict__ out)
{
    const int i4 = blockIdx.x * 256 + threadIdx.x;   // float4 index
    constexpr int kTot = kB * kO * kHW;              // 524288
    if (i4 * 4 >= kTot) return;

    const float4* p4 = reinterpret_cast<const float4*>(part);
    float4 s = p4[i4];
    #pragma unroll
    for (int n = 1; n < NC; ++n) {
        float4 v = p4[(size_t)n * (kTot / 4) + i4];
        s.x += v.x; s.y += v.y; s.z += v.z; s.w += v.w;
    }
    const int o  = ((i4 * 4) >> 10) & (kO - 1);      // HW = 1024
    const float bo = bias[o];
    s.x += bo; s.y += bo; s.z += bo; s.w += bo;
    reinterpret_cast<float4*>(out)[i4] = s;
}

extern "C" void kernel_launch(void* const* d_in, const int* in_sizes, int n_in,
                              void* d_out, int out_size, void* d_ws, size_t ws_size,
                              hipStream_t stream)
{
    const float* x       = (const float*)d_in[0];
    const float* means   = (const float*)d_in[1];
    const float* bias    = (const float*)d_in[2];
    const int*   col_idx = (const int*)d_in[3];
    float*       out     = (float*)d_out;
    float*       part    = (float*)d_ws;

    constexpr int NC = 4;
    constexpr size_t kPartBytes = (size_t)NC * kB * kO * kHW * sizeof(float); // 8 MB

    if (ws_size >= kPartBytes) {
        conv_kernel<NC, false><<<NC * kB * kO, 256, 0, stream>>>(
            x, means, bias, col_idx, part);
        reduce_kernel<NC><<<(kB * kO * kHW / 4 + 255) / 256, 256, 0, stream>>>(
            part, bias, out);
    } else {
        // Fallback: single-chunk direct path (no workspace needed)
        conv_kernel<1, true><<<kB * kO, 256, 0, stream>>>(
            x, means, bias, col_idx, out);
    }
}